// Round 5
// baseline (97.498 us; speedup 1.0000x reference)
//
#include <hip/hip_runtime.h>

#define K_RECENT 10

typedef float f32x4 __attribute__((ext_vector_type(4)));
typedef int   i32x4 __attribute__((ext_vector_type(4)));

// ---------------------------------------------------------------------------
// Kernel 1: user_pref[b, :] = masked mean of region_emb over last-10 valid
// positions. One block per b, 128 threads (= D).
// ---------------------------------------------------------------------------
__global__ void pref_kernel(const int* __restrict__ user_seq,
                            const int* __restrict__ user_seq_len,
                            const int* __restrict__ poi_region_id,
                            const float* __restrict__ region_emb,
                            float* __restrict__ pref,
                            int S, int D) {
    int b = blockIdx.x;
    int tid = threadIdx.x;
    __shared__ int rids[K_RECENT];

    int len = user_seq_len[b];
    if (tid < K_RECENT) {
        int pos = len - K_RECENT + tid;
        int r = -1;
        if (pos >= 0) {
            int poi = user_seq[b * S + pos];
            r = poi_region_id[poi];
        }
        rids[tid] = r;
    }
    __syncthreads();

    float acc = 0.f;
    int cnt = 0;
#pragma unroll
    for (int j = 0; j < K_RECENT; ++j) {
        int r = rids[j];
        if (r >= 0) {
            ++cnt;
            acc += region_emb[r * D + tid];
        }
    }
    float c = (cnt > 0) ? (float)cnt : 1.f;
    pref[b * D + tid] = acc / c;
}

// ---------------------------------------------------------------------------
// Kernel 2: scores[b, r] = pref[b] . region_emb[r]  (B x R, K = 128)
// ---------------------------------------------------------------------------
__global__ void scores_kernel(const float* __restrict__ pref,
                              const float* __restrict__ region_emb,
                              float* __restrict__ scores,
                              int R) {
    const int BT = 8;          // batch rows per block
    const int D  = 128;
    __shared__ float pl[BT * D];

    int tid = threadIdx.x;
    int b0  = blockIdx.y * BT;

    ((f32x4*)pl)[tid] = ((const f32x4*)(pref + (size_t)b0 * D))[tid];
    __syncthreads();

    int r = blockIdx.x * blockDim.x + tid;
    if (r >= R) return;

    float acc[BT];
#pragma unroll
    for (int bb = 0; bb < BT; ++bb) acc[bb] = 0.f;

    const f32x4* erow = (const f32x4*)(region_emb + (size_t)r * D);
#pragma unroll 8
    for (int d4 = 0; d4 < D / 4; ++d4) {
        f32x4 e = erow[d4];
#pragma unroll
        for (int bb = 0; bb < BT; ++bb) {
            f32x4 pv = *reinterpret_cast<const f32x4*>(&pl[bb * D + d4 * 4]);
            acc[bb] = fmaf(e.x, pv.x,
                      fmaf(e.y, pv.y,
                      fmaf(e.z, pv.z,
                      fmaf(e.w, pv.w, acc[bb]))));
        }
    }
#pragma unroll
    for (int bb = 0; bb < BT; ++bb)
        scores[(size_t)(b0 + bb) * R + r] = acc[bb];
}

// ---------------------------------------------------------------------------
// Kernel 3: out[b, l] = pred[b, l] + alpha * scores[b, poi_region_id[l]]
// BB=4 batch rows per block: one rid load feeds 4 independent
// gather+fma+store streams (4x MLP, 4x less rid traffic). Score rows in LDS.
// ---------------------------------------------------------------------------
#define OUT_BLOCK   256
#define OUT_F       4
#define BB          4
#define MAX_R       2048
#define ROW_PAD     (MAX_R + 4)

__global__ void out_kernel_multi(const float* __restrict__ pred,
                                 const float* __restrict__ scores,
                                 const int* __restrict__ rid,
                                 const float* __restrict__ alpha_p,
                                 float* __restrict__ out,
                                 int L4, int L, int R, int CPB) {
    __shared__ float srow[BB][ROW_PAD];
    int b0  = blockIdx.y * BB;
    int tid = threadIdx.x;
    float alpha = alpha_p[0];

    // Cooperative coalesced fill of BB score rows.
    int R4 = R >> 2;
#pragma unroll
    for (int bb = 0; bb < BB; ++bb) {
        const float* g = scores + (size_t)(b0 + bb) * R;
        for (int i = tid; i < R4; i += OUT_BLOCK)
            ((f32x4*)srow[bb])[i] = ((const f32x4*)g)[i];
        for (int i = (R4 << 2) + tid; i < R; i += OUT_BLOCK)
            srow[bb][i] = g[i];
    }
    __syncthreads();

    int base = blockIdx.x * CPB;
    int n = min(CPB, L4 - base);
    if (n <= 0) return;

    const i32x4* rp = (const i32x4*)rid + base;
    const f32x4* pp[BB];
    f32x4*       op[BB];
#pragma unroll
    for (int bb = 0; bb < BB; ++bb) {
        pp[bb] = (const f32x4*)(pred + (size_t)(b0 + bb) * L) + base;
        op[bb] = (f32x4*)(out + (size_t)(b0 + bb) * L) + base;
    }

    int full = n >> 8;                 // full (unchecked) 256-wide rounds
#pragma unroll 2
    for (int k = 0; k < full; ++k) {
        int i = k * OUT_BLOCK + tid;
        i32x4 r4 = rp[i];
#pragma unroll
        for (int bb = 0; bb < BB; ++bb) {
            f32x4 p = pp[bb][i];
            f32x4 o;
            o.x = fmaf(alpha, srow[bb][r4.x], p.x);
            o.y = fmaf(alpha, srow[bb][r4.y], p.y);
            o.z = fmaf(alpha, srow[bb][r4.z], p.z);
            o.w = fmaf(alpha, srow[bb][r4.w], p.w);
            __builtin_nontemporal_store(o, &op[bb][i]);
        }
    }
    int i = full * OUT_BLOCK + tid;
    if (i < n) {
        i32x4 r4 = rp[i];
#pragma unroll
        for (int bb = 0; bb < BB; ++bb) {
            f32x4 p = pp[bb][i];
            f32x4 o;
            o.x = fmaf(alpha, srow[bb][r4.x], p.x);
            o.y = fmaf(alpha, srow[bb][r4.y], p.y);
            o.z = fmaf(alpha, srow[bb][r4.z], p.z);
            o.w = fmaf(alpha, srow[bb][r4.w], p.w);
            __builtin_nontemporal_store(o, &op[bb][i]);
        }
    }
}

// Fallback: direct L1 gather (R > MAX_R, B % BB != 0, or ragged tail).
__global__ void out_kernel_scalar(const float* __restrict__ pred,
                                  const float* __restrict__ scores,
                                  const int* __restrict__ rid,
                                  const float* __restrict__ alpha_p,
                                  float* __restrict__ out,
                                  int l0, int L, int R) {
    int b = blockIdx.y;
    int l = l0 + blockIdx.x * blockDim.x + threadIdx.x;
    if (l >= L) return;
    float alpha = alpha_p[0];
    out[(size_t)b * L + l] =
        fmaf(alpha, scores[(size_t)b * R + rid[l]], pred[(size_t)b * L + l]);
}

extern "C" void kernel_launch(void* const* d_in, const int* in_sizes, int n_in,
                              void* d_out, int out_size, void* d_ws, size_t ws_size,
                              hipStream_t stream) {
    const float* pred_base     = (const float*)d_in[0];
    const int*   user_seq      = (const int*)d_in[1];
    const int*   user_seq_len  = (const int*)d_in[2];
    const int*   poi_region_id = (const int*)d_in[3];
    const float* region_emb    = (const float*)d_in[4];
    const float* alpha         = (const float*)d_in[5];
    float*       out           = (float*)d_out;

    const int B = in_sizes[2];              // 1024
    const int S = in_sizes[1] / B;          // 200
    const int L = in_sizes[3];              // 50000
    const int D = 128;
    const int R = in_sizes[4] / D;          // 2000

    // Workspace layout: scores [B*R] f32, pref [B*D] f32  (~8.7 MB total)
    float* scores = (float*)d_ws;
    float* pref   = scores + (size_t)B * R;

    // 1) user_pref
    pref_kernel<<<B, D, 0, stream>>>(user_seq, user_seq_len, poi_region_id,
                                     region_emb, pref, S, D);

    // 2) scores[B,R]
    dim3 g2((R + 255) / 256, B / 8);
    scores_kernel<<<g2, 256, 0, stream>>>(pref, region_emb, scores, R);

    // 3) output
    int L4 = L / 4;
    if (L4 > 0) {
        if (R <= MAX_R && (B % BB) == 0) {
            int CPB = (L4 + OUT_F - 1) / OUT_F;
            dim3 g3(OUT_F, B / BB);
            out_kernel_multi<<<g3, OUT_BLOCK, 0, stream>>>(
                pred_base, scores, poi_region_id, alpha, out, L4, L, R, CPB);
        } else {
            dim3 gt(((L4 * 4) + 255) / 256, B);
            out_kernel_scalar<<<gt, 256, 0, stream>>>(
                pred_base, scores, poi_region_id, alpha, out, 0, L4 * 4, R);
        }
    }
    int tail = L - L4 * 4;
    if (tail > 0) {
        dim3 gt(1, B);
        out_kernel_scalar<<<gt, 64, 0, stream>>>(pred_base, scores, poi_region_id,
                                                 alpha, out, L4 * 4, L, R);
    }
}

// Round 6
// 96.230 us; speedup vs baseline: 1.0132x; 1.0132x over previous
//
#include <hip/hip_runtime.h>

#define K_RECENT 10

typedef float f32x4 __attribute__((ext_vector_type(4)));
typedef int   i32x4 __attribute__((ext_vector_type(4)));

// ---------------------------------------------------------------------------
// Kernel 1: user_pref[b, :] = masked mean of region_emb over last-10 valid
// positions. One block per b, 128 threads (= D).
// ---------------------------------------------------------------------------
__global__ void pref_kernel(const int* __restrict__ user_seq,
                            const int* __restrict__ user_seq_len,
                            const int* __restrict__ poi_region_id,
                            const float* __restrict__ region_emb,
                            float* __restrict__ pref,
                            int S, int D) {
    int b = blockIdx.x;
    int tid = threadIdx.x;
    __shared__ int rids[K_RECENT];

    int len = user_seq_len[b];
    if (tid < K_RECENT) {
        int pos = len - K_RECENT + tid;
        int r = -1;
        if (pos >= 0) {
            int poi = user_seq[b * S + pos];
            r = poi_region_id[poi];
        }
        rids[tid] = r;
    }
    __syncthreads();

    float acc = 0.f;
    int cnt = 0;
#pragma unroll
    for (int j = 0; j < K_RECENT; ++j) {
        int r = rids[j];
        if (r >= 0) {
            ++cnt;
            acc += region_emb[r * D + tid];
        }
    }
    float c = (cnt > 0) ? (float)cnt : 1.f;
    pref[b * D + tid] = acc / c;
}

// ---------------------------------------------------------------------------
// Kernel 2: scores[b, r] = pref[b] . region_emb[r]  (B x R, K = 128)
// ---------------------------------------------------------------------------
__global__ void scores_kernel(const float* __restrict__ pref,
                              const float* __restrict__ region_emb,
                              float* __restrict__ scores,
                              int R) {
    const int BT = 8;          // batch rows per block
    const int D  = 128;
    __shared__ float pl[BT * D];

    int tid = threadIdx.x;
    int b0  = blockIdx.y * BT;

    ((f32x4*)pl)[tid] = ((const f32x4*)(pref + (size_t)b0 * D))[tid];
    __syncthreads();

    int r = blockIdx.x * blockDim.x + tid;
    if (r >= R) return;

    float acc[BT];
#pragma unroll
    for (int bb = 0; bb < BT; ++bb) acc[bb] = 0.f;

    const f32x4* erow = (const f32x4*)(region_emb + (size_t)r * D);
#pragma unroll 8
    for (int d4 = 0; d4 < D / 4; ++d4) {
        f32x4 e = erow[d4];
#pragma unroll
        for (int bb = 0; bb < BT; ++bb) {
            f32x4 pv = *reinterpret_cast<const f32x4*>(&pl[bb * D + d4 * 4]);
            acc[bb] = fmaf(e.x, pv.x,
                      fmaf(e.y, pv.y,
                      fmaf(e.z, pv.z,
                      fmaf(e.w, pv.w, acc[bb]))));
        }
    }
#pragma unroll
    for (int bb = 0; bb < BT; ++bb)
        scores[(size_t)(b0 + bb) * R + r] = acc[bb];
}

// ---------------------------------------------------------------------------
// Kernel 3: out[b, l] = pred[b, l] + alpha * scores[b, poi_region_id[l]]
// BB=1 (high occupancy, 8 KB LDS) + explicit 4-round load batching: 4 rid +
// 4 pred loads issued into registers before any LDS gather, so each wave
// holds ~128 B of reads in flight (deep vmcnt pipeline). nt stores keep L3
// clean for pred.
// ---------------------------------------------------------------------------
#define OUT_BLOCK   256
#define OUT_F       4
#define PIPE        4
#define MAX_R       2048

__global__ void out_kernel_pipe(const float* __restrict__ pred,
                                const float* __restrict__ scores,
                                const int* __restrict__ rid,
                                const float* __restrict__ alpha_p,
                                float* __restrict__ out,
                                int L4, int L, int R, int CPB) {
    __shared__ float srow[MAX_R];
    int b   = blockIdx.y;
    int tid = threadIdx.x;
    float alpha = alpha_p[0];

    // Cooperative coalesced fill of the score row.
    const float* g = scores + (size_t)b * R;
    int R4 = R >> 2;
    for (int i = tid; i < R4; i += OUT_BLOCK)
        ((f32x4*)srow)[i] = ((const f32x4*)g)[i];
    for (int i = (R4 << 2) + tid; i < R; i += OUT_BLOCK)
        srow[i] = g[i];
    __syncthreads();

    int base = blockIdx.x * CPB;
    int n = min(CPB, L4 - base);
    if (n <= 0) return;

    const i32x4* rp = (const i32x4*)rid + base;
    const f32x4* pp = (const f32x4*)(pred + (size_t)b * L) + base;
    f32x4*       op = (f32x4*)(out + (size_t)b * L) + base;

    int rounds  = n >> 8;            // full 256-wide rounds
    int batches = rounds / PIPE;     // groups of PIPE rounds

    for (int kb = 0; kb < batches; ++kb) {
        int i0 = kb * (PIPE * OUT_BLOCK) + tid;
        i32x4 r4[PIPE];
        f32x4 p[PIPE];
        // Issue all loads first: 2*PIPE vmem ops in flight before first use.
#pragma unroll
        for (int j = 0; j < PIPE; ++j) r4[j] = rp[i0 + j * OUT_BLOCK];
#pragma unroll
        for (int j = 0; j < PIPE; ++j) p[j]  = pp[i0 + j * OUT_BLOCK];
#pragma unroll
        for (int j = 0; j < PIPE; ++j) {
            f32x4 o;
            o.x = fmaf(alpha, srow[r4[j].x], p[j].x);
            o.y = fmaf(alpha, srow[r4[j].y], p[j].y);
            o.z = fmaf(alpha, srow[r4[j].z], p[j].z);
            o.w = fmaf(alpha, srow[r4[j].w], p[j].w);
            __builtin_nontemporal_store(o, &op[i0 + j * OUT_BLOCK]);
        }
    }
    // Leftover full rounds.
    for (int k = batches * PIPE; k < rounds; ++k) {
        int i = k * OUT_BLOCK + tid;
        i32x4 r4 = rp[i];
        f32x4 p  = pp[i];
        f32x4 o;
        o.x = fmaf(alpha, srow[r4.x], p.x);
        o.y = fmaf(alpha, srow[r4.y], p.y);
        o.z = fmaf(alpha, srow[r4.z], p.z);
        o.w = fmaf(alpha, srow[r4.w], p.w);
        __builtin_nontemporal_store(o, &op[i]);
    }
    // Masked tail.
    int i = rounds * OUT_BLOCK + tid;
    if (i < n) {
        i32x4 r4 = rp[i];
        f32x4 p  = pp[i];
        f32x4 o;
        o.x = fmaf(alpha, srow[r4.x], p.x);
        o.y = fmaf(alpha, srow[r4.y], p.y);
        o.z = fmaf(alpha, srow[r4.z], p.z);
        o.w = fmaf(alpha, srow[r4.w], p.w);
        __builtin_nontemporal_store(o, &op[i]);
    }
}

// Fallback: direct L1 gather (R > MAX_R, or ragged tail).
__global__ void out_kernel_scalar(const float* __restrict__ pred,
                                  const float* __restrict__ scores,
                                  const int* __restrict__ rid,
                                  const float* __restrict__ alpha_p,
                                  float* __restrict__ out,
                                  int l0, int L, int R) {
    int b = blockIdx.y;
    int l = l0 + blockIdx.x * blockDim.x + threadIdx.x;
    if (l >= L) return;
    float alpha = alpha_p[0];
    out[(size_t)b * L + l] =
        fmaf(alpha, scores[(size_t)b * R + rid[l]], pred[(size_t)b * L + l]);
}

extern "C" void kernel_launch(void* const* d_in, const int* in_sizes, int n_in,
                              void* d_out, int out_size, void* d_ws, size_t ws_size,
                              hipStream_t stream) {
    const float* pred_base     = (const float*)d_in[0];
    const int*   user_seq      = (const int*)d_in[1];
    const int*   user_seq_len  = (const int*)d_in[2];
    const int*   poi_region_id = (const int*)d_in[3];
    const float* region_emb    = (const float*)d_in[4];
    const float* alpha         = (const float*)d_in[5];
    float*       out           = (float*)d_out;

    const int B = in_sizes[2];              // 1024
    const int S = in_sizes[1] / B;          // 200
    const int L = in_sizes[3];              // 50000
    const int D = 128;
    const int R = in_sizes[4] / D;          // 2000

    // Workspace layout: scores [B*R] f32, pref [B*D] f32  (~8.7 MB total)
    float* scores = (float*)d_ws;
    float* pref   = scores + (size_t)B * R;

    // 1) user_pref
    pref_kernel<<<B, D, 0, stream>>>(user_seq, user_seq_len, poi_region_id,
                                     region_emb, pref, S, D);

    // 2) scores[B,R]
    dim3 g2((R + 255) / 256, B / 8);
    scores_kernel<<<g2, 256, 0, stream>>>(pref, region_emb, scores, R);

    // 3) output
    int L4 = L / 4;
    if (L4 > 0) {
        if (R <= MAX_R) {
            int CPB = (L4 + OUT_F - 1) / OUT_F;
            dim3 g3(OUT_F, B);
            out_kernel_pipe<<<g3, OUT_BLOCK, 0, stream>>>(
                pred_base, scores, poi_region_id, alpha, out, L4, L, R, CPB);
        } else {
            dim3 gt(((L4 * 4) + 255) / 256, B);
            out_kernel_scalar<<<gt, 256, 0, stream>>>(
                pred_base, scores, poi_region_id, alpha, out, 0, L4 * 4, R);
        }
    }
    int tail = L - L4 * 4;
    if (tail > 0) {
        dim3 gt(1, B);
        out_kernel_scalar<<<gt, 64, 0, stream>>>(pred_base, scores, poi_region_id,
                                                 alpha, out, L4 * 4, L, R);
    }
}